// Round 6
// baseline (171.864 us; speedup 1.0000x reference)
//
#include <hip/hip_runtime.h>
#include <hip/hip_bf16.h>

#define M_DIM 2048   // size
#define K_DIM 2048   // prev_size
#define N_DIM 8192   // batch

#define BM 128
#define BN 256
#define BK 64
#define NT (K_DIM / BK)   // 32 K-tiles

typedef __attribute__((ext_vector_type(16))) float f32x16;
typedef __attribute__((ext_vector_type(8))) short s16x8;

static __device__ __forceinline__ ushort f2bf(float x) {
    __hip_bfloat16 h = __float2bfloat16(x);
    return *reinterpret_cast<ushort*>(&h);
}

// async global->LDS: each lane contributes 16B; LDS dest is wave-uniform base,
// hardware writes base + lane*16 (linear).
static __device__ __forceinline__ void stage1k(const ushort* g, ushort* l) {
    __builtin_amdgcn_global_load_lds(
        (const __attribute__((address_space(1))) void*)g,
        (__attribute__((address_space(3))) void*)l, 16, 0, 0);
}

// ---------------- softmax over rows of Wa/Wb -> bf16 probabilities ----------
__global__ __launch_bounds__(256) void softmax_rows_kernel(
    const float* __restrict__ Wa, const float* __restrict__ Wb,
    ushort* __restrict__ Pa, ushort* __restrict__ Pb)
{
    const float* W = blockIdx.y ? Wb : Wa;
    ushort* P = blockIdx.y ? Pb : Pa;
    const int row = blockIdx.x;
    const int t = threadIdx.x;
    const float* w = W + (size_t)row * K_DIM + t * 8;
    float4 v0 = *(const float4*)(w);
    float4 v1 = *(const float4*)(w + 4);
    float x[8] = {v0.x, v0.y, v0.z, v0.w, v1.x, v1.y, v1.z, v1.w};

    float m = x[0];
#pragma unroll
    for (int i = 1; i < 8; ++i) m = fmaxf(m, x[i]);
#pragma unroll
    for (int off = 32; off >= 1; off >>= 1) m = fmaxf(m, __shfl_xor(m, off));
    __shared__ float redm[4], reds[4];
    const int wid = t >> 6;
    if ((t & 63) == 0) redm[wid] = m;
    __syncthreads();
    m = fmaxf(fmaxf(redm[0], redm[1]), fmaxf(redm[2], redm[3]));

    float s = 0.f;
#pragma unroll
    for (int i = 0; i < 8; ++i) { x[i] = __expf(x[i] - m); s += x[i]; }
#pragma unroll
    for (int off = 32; off >= 1; off >>= 1) s += __shfl_xor(s, off);
    if ((t & 63) == 0) reds[wid] = s;
    __syncthreads();
    s = reds[0] + reds[1] + reds[2] + reds[3];
    const float inv = 1.0f / s;

    union { ushort u[8]; int4 v; } pk;
#pragma unroll
    for (int i = 0; i < 8; ++i) pk.u[i] = f2bf(x[i] * inv);
    *(int4*)(P + (size_t)row * K_DIM + t * 8) = pk.v;
}

// ---------- table softmax (over 16) contracted with gate coeffs -> c[4][M] --
__global__ __launch_bounds__(256) void table_c_kernel(
    const float* __restrict__ TW, float4* __restrict__ C4)
{
    const int s = blockIdx.x * 256 + threadIdx.x;
    if (s >= M_DIM) return;
    float x[16];
    float m = -1e30f;
#pragma unroll
    for (int t = 0; t < 16; ++t) { x[t] = TW[t * M_DIM + s]; m = fmaxf(m, x[t]); }
    float sum = 0.f;
#pragma unroll
    for (int t = 0; t < 16; ++t) { x[t] = __expf(x[t] - m); sum += x[t]; }
    const float inv = 1.0f / sum;

    const float c0a[16] = {0,0,0,0,0,0,0,0, 1,1,1,1,1,1,1,1};
    const float cAa[16] = {0,0,1,1,0,0,1,1, -1,-1,0,0,-1,-1,0,0};
    const float cBa[16] = {0,0,0,0,1,1,1,1, -1,-1,-1,-1,0,0,0,0};
    const float cXa[16] = {0,1,-1,0,-1,0,-2,-1, 1,2,0,1,0,1,-1,0};
    float c0 = 0.f, cA = 0.f, cB = 0.f, cX = 0.f;
#pragma unroll
    for (int t = 0; t < 16; ++t) {
        const float p = x[t] * inv;
        c0 += p * c0a[t]; cA += p * cAa[t]; cB += p * cBa[t]; cX += p * cXa[t];
    }
    C4[s] = make_float4(c0, cA, cB, cX);
}

// ---------- prev [K][N] f32 -> prevT [N][K] bf16 (transpose + convert) ------
__global__ __launch_bounds__(256) void transp_conv_kernel(
    const float* __restrict__ src, ushort* __restrict__ dst)
{
    __shared__ ushort tile[64][72];
    const int n0 = blockIdx.x * 64;
    const int k0 = blockIdx.y * 64;
    const int t = threadIdx.x;
#pragma unroll
    for (int it = 0; it < 4; ++it) {
        const int lin = it * 256 + t;      // 0..1023
        const int k = lin >> 4;            // 0..63
        const int n4 = (lin & 15) * 4;     // 0..60
        float4 v = *(const float4*)(src + (size_t)(k0 + k) * N_DIM + n0 + n4);
        tile[n4 + 0][k] = f2bf(v.x);
        tile[n4 + 1][k] = f2bf(v.y);
        tile[n4 + 2][k] = f2bf(v.z);
        tile[n4 + 3][k] = f2bf(v.w);
    }
    __syncthreads();
#pragma unroll
    for (int it = 0; it < 2; ++it) {
        const int lin = it * 256 + t;      // 0..511
        const int n = lin >> 3;            // 0..63
        const int k8 = (lin & 7) * 8;      // 0..56
        int4 v = *(const int4*)&tile[n][k8];
        *(int4*)(dst + (size_t)(n0 + n) * K_DIM + k0 + k8) = v;
    }
}

// -------- dual GEMM, 32x32x16 MFMA, 2-barrier/tile schedule + epilogue ------
// LDS: [buf][kh][rows][32] bf16 per operand; 16B-slot swizzle sigma(r)=(r>>1)&3
// (write: pre-swizzled global col; read: same XOR). Conflict-free for both the
// staging writes and the 32-row fragment reads (8 lanes per 4-bank group).
//
// Per tile: 2 halves (kh0/kh1), each = 4 slots of {lgkm0; 4x mfma_32x32x16;
// issue next ds_reads (+stage pair)}. One barrier per half.
// Stage pairs: C,D(t+1) issued in half 1; A,B(t+2) issued in half 2.
// Guards: vmcnt(4) at each half end (FIFO drains exactly the pairs the
// following barrier publishes: g1 -> A,B(t+1) for BARb; g2 -> C,D(t+1) for
// BARa(t+1)). Tail (kt >= NT-2): vmcnt(0).
//
// mfma_f32_32x32x16_bf16 layouts: A/B per-lane 8 K-contig elems at
// row/col = lane&31, k-group = lane>>5 (32-row analog of the verified
// 16x16x32 layout). C/D: col = lane&31, row = (reg&3) + 8*(reg>>2) +
// 4*(lane>>5)  [m74/m101].

#define MFMA4(ACC, FA, FP)                                                     \
    _Pragma("unroll") for (int mi = 0; mi < 2; ++mi)                           \
    _Pragma("unroll") for (int ni = 0; ni < 2; ++ni)                           \
        ACC[mi][ni] = __builtin_amdgcn_mfma_f32_32x32x16_bf16(                 \
            FA[mi], FP[ni], ACC[mi][ni], 0, 0, 0);

#define SB() __builtin_amdgcn_sched_barrier(0)

#define LGKM0_FENCE()                                                          \
    do {                                                                       \
        asm volatile("s_waitcnt lgkmcnt(0)" ::: "memory");                     \
        __builtin_amdgcn_sched_barrier(0);                                     \
    } while (0)

#define RD_A(DST, BASE, SL)                                                    \
    _Pragma("unroll") for (int i = 0; i < 2; ++i)                              \
        DST[i] = *(const s16x8*)((BASE) + roA + i * 2048 + (SL));
#define RD_P(DST, BASE, SL)                                                    \
    _Pragma("unroll") for (int i = 0; i < 2; ++i)                              \
        DST[i] = *(const s16x8*)((BASE) + roP + i * 2048 + (SL));

#define STAGE_A(T) do { const int b_ = (T) & 1; const int o_ = (T) * BK;       \
    stage1k(gPa + o_,  &sPa[b_][0][wid * 16][0]);                              \
    stage1k(gPt0 + o_, &sPt[b_][0][wid * 16][0]); } while (0)
#define STAGE_B(T) do { const int b_ = (T) & 1; const int o_ = (T) * BK;       \
    stage1k(gPt1 + o_, &sPt[b_][0][128 + wid * 16][0]);                        \
    stage1k(gPb + o_,  &sPb[b_][0][wid * 16][0]); } while (0)
#define STAGE_C(T) do { const int b_ = (T) & 1; const int o_ = (T) * BK + 32;  \
    stage1k(gPa + o_,  &sPa[b_][1][wid * 16][0]);                              \
    stage1k(gPt0 + o_, &sPt[b_][1][wid * 16][0]); } while (0)
#define STAGE_D(T) do { const int b_ = (T) & 1; const int o_ = (T) * BK + 32;  \
    stage1k(gPt1 + o_, &sPt[b_][1][128 + wid * 16][0]);                        \
    stage1k(gPb + o_,  &sPb[b_][1][wid * 16][0]); } while (0)

__global__ __launch_bounds__(512, 2) void logic_gemm_kernel(
    const ushort* __restrict__ Pa,   // [M][K] bf16
    const ushort* __restrict__ Pb,   // [M][K] bf16
    const ushort* __restrict__ Pt,   // prevT [N][K] bf16
    const float4* __restrict__ C4,   // [M]
    float* __restrict__ out)         // [M][N]
{
    __shared__ ushort sPa[2][2][128][32];   // 32 KB
    __shared__ ushort sPb[2][2][128][32];   // 32 KB
    __shared__ ushort sPt[2][2][256][32];   // 64 KB

    const int m0 = blockIdx.y * BM;
    const int n0 = blockIdx.x * BN;
    const int t = threadIdx.x;
    const int wid = t >> 6, lane = t & 63;
    const int wr = wid >> 2, wc = wid & 3;   // 2M x 4N waves, 64x64 out each
    const int lrow = lane & 31;              // fragment row/col within 32-block
    const int khalf = lane >> 5;             // k-subgroup (8 elems each)

    // staging: lane -> region row (lane>>2), pre-swizzled source col
    const int srow = lane >> 2;                               // 0..15
    const int scol = (((lane & 3) ^ ((lane >> 3) & 3)) << 3); // {0,8,16,24}
    const ushort* gPa  = Pa + (size_t)(m0 + wid * 16 + srow) * K_DIM + scol;
    const ushort* gPb  = Pb + (size_t)(m0 + wid * 16 + srow) * K_DIM + scol;
    const ushort* gPt0 = Pt + (size_t)(n0 + wid * 16 + srow) * K_DIM + scol;
    const ushort* gPt1 = gPt0 + (size_t)128 * K_DIM;

    // ds_read offsets: row*64 + phys_slot*16; phys = (ks*2 + khalf) ^ sigma,
    // sigma = (lrow>>1)&3 (row bases are multiples of 32 -> lane-only).
    const int sig = (lrow >> 1) & 3;
    const int sl0 = ((0 | khalf) ^ sig) << 4;   // ks=0
    const int sl1 = ((2 | khalf) ^ sig) << 4;   // ks=1
    const int roA = (wr * 64 + lrow) * 64;      // within [128][32] region
    const int roP = (wc * 64 + lrow) * 64;      // within [256][32] region

    f32x16 accA[2][2] = {};
    f32x16 accB[2][2] = {};
    s16x8 rA[2], rP[2], rB[2], rA2[2], rP2[2], rB2[2];

    // prologue: A,B(0) C,D(0) A,B(1) = 12 loads (FIFO order!); drain A..D(0).
    STAGE_A(0); STAGE_B(0); STAGE_C(0); STAGE_D(0);
    STAGE_A(1); STAGE_B(1);
    asm volatile("s_waitcnt vmcnt(4)" ::: "memory");
    __builtin_amdgcn_s_barrier();
    {
        const char* bA0 = (const char*)&sPa[0][0][0][0];
        const char* bP0 = (const char*)&sPt[0][0][0][0];
        RD_A(rA, bA0, sl0);
        RD_P(rP, bP0, sl0);
    }

    for (int kt = 0; kt < NT; ++kt) {
        const int buf = kt & 1;
        const char* bA0 = (const char*)&sPa[buf][0][0][0];
        const char* bA1 = (const char*)&sPa[buf][1][0][0];
        const char* bB0 = (const char*)&sPb[buf][0][0][0];
        const char* bB1 = (const char*)&sPb[buf][1][0][0];
        const char* bP0 = (const char*)&sPt[buf][0][0][0];
        const char* bP1 = (const char*)&sPt[buf][1][0][0];
        const char* nA0 = (const char*)&sPa[buf ^ 1][0][0][0];
        const char* nP0 = (const char*)&sPt[buf ^ 1][0][0][0];

        // ================= half 1: kh0 =================
        LGKM0_FENCE();
        __builtin_amdgcn_s_setprio(1);
        MFMA4(accA, rA, rP);
        __builtin_amdgcn_s_setprio(0);
        SB();
        RD_A(rB, bB0, sl0);
        if (kt + 1 < NT) STAGE_C(kt + 1);
        SB();

        LGKM0_FENCE();
        __builtin_amdgcn_s_setprio(1);
        MFMA4(accB, rB, rP);
        __builtin_amdgcn_s_setprio(0);
        SB();
        RD_A(rA2, bA0, sl1);
        RD_P(rP2, bP0, sl1);
        if (kt + 1 < NT) STAGE_D(kt + 1);
        SB();

        LGKM0_FENCE();
        __builtin_amdgcn_s_setprio(1);
        MFMA4(accA, rA2, rP2);
        __builtin_amdgcn_s_setprio(0);
        SB();
        RD_A(rB2, bB0, sl1);
        SB();

        LGKM0_FENCE();
        __builtin_amdgcn_s_setprio(1);
        MFMA4(accB, rB2, rP2);
        __builtin_amdgcn_s_setprio(0);
        SB();
        RD_A(rA, bA1, sl0);          // kh1 ks0 (published at BARa(t))
        RD_P(rP, bP1, sl0);
        if (kt < NT - 2) asm volatile("s_waitcnt vmcnt(4)" ::: "memory");
        else             asm volatile("s_waitcnt vmcnt(0)" ::: "memory");
        SB();
        __builtin_amdgcn_s_barrier();   // BARb: publishes A,B(t+1)

        // ================= half 2: kh1 =================
        LGKM0_FENCE();
        __builtin_amdgcn_s_setprio(1);
        MFMA4(accA, rA, rP);
        __builtin_amdgcn_s_setprio(0);
        SB();
        RD_A(rB, bB1, sl0);
        if (kt + 2 < NT) STAGE_A(kt + 2);
        SB();

        LGKM0_FENCE();
        __builtin_amdgcn_s_setprio(1);
        MFMA4(accB, rB, rP);
        __builtin_amdgcn_s_setprio(0);
        SB();
        RD_A(rA2, bA1, sl1);
        RD_P(rP2, bP1, sl1);
        if (kt + 2 < NT) STAGE_B(kt + 2);
        SB();

        LGKM0_FENCE();
        __builtin_amdgcn_s_setprio(1);
        MFMA4(accA, rA2, rP2);
        __builtin_amdgcn_s_setprio(0);
        SB();
        RD_A(rB2, bB1, sl1);
        SB();

        LGKM0_FENCE();
        __builtin_amdgcn_s_setprio(1);
        MFMA4(accB, rB2, rP2);
        __builtin_amdgcn_s_setprio(0);
        SB();
        RD_A(rA, nA0, sl0);          // next tile kh0 ks0 (published at BARb(t))
        RD_P(rP, nP0, sl0);
        if (kt < NT - 2) asm volatile("s_waitcnt vmcnt(4)" ::: "memory");
        else             asm volatile("s_waitcnt vmcnt(0)" ::: "memory");
        SB();
        __builtin_amdgcn_s_barrier();   // BARa(t+1): publishes C,D(t+1)
    }

    // epilogue: out = c0 + cA*A + cB*B + cAB*A*B
    // 32x32 C/D: col = lane&31, row = (j&3) + 8*(j>>2) + 4*khalf
#pragma unroll
    for (int mi = 0; mi < 2; ++mi) {
#pragma unroll
        for (int j = 0; j < 16; ++j) {
            const int rloc = (j & 3) + 8 * (j >> 2) + 4 * khalf;
            const int row = m0 + wr * 64 + mi * 32 + rloc;
            const float4 c = C4[row];
#pragma unroll
            for (int ni = 0; ni < 2; ++ni) {
                const int col = n0 + wc * 64 + ni * 32 + lrow;
                const float Av = accA[mi][ni][j];
                const float Bv = accB[mi][ni][j];
                out[(size_t)row * N_DIM + col] = c.x + c.y * Av + c.z * Bv + c.w * Av * Bv;
            }
        }
    }
}

extern "C" void kernel_launch(void* const* d_in, const int* in_sizes, int n_in,
                              void* d_out, int out_size, void* d_ws, size_t ws_size,
                              hipStream_t stream) {
    const float* prev = (const float*)d_in[0];   // [2048][8192]
    const float* Wa   = (const float*)d_in[1];   // [2048][2048]
    const float* Wb   = (const float*)d_in[2];   // [2048][2048]
    const float* TW   = (const float*)d_in[3];   // [16][2048]
    float* out = (float*)d_out;                  // [2048][8192]

    char* ws = (char*)d_ws;
    ushort* Pa = (ushort*)(ws);                          //  8 MiB
    ushort* Pb = (ushort*)(ws + (size_t)(8u << 20));     //  8 MiB
    ushort* Pt = (ushort*)(ws + (size_t)(16u << 20));    // 32 MiB
    float4* C4 = (float4*)(ws + (size_t)(48u << 20));    // 32 KiB

    softmax_rows_kernel<<<dim3(2048, 2), 256, 0, stream>>>(Wa, Wb, Pa, Pb);
    table_c_kernel<<<dim3(8), 256, 0, stream>>>(TW, C4);
    transp_conv_kernel<<<dim3(N_DIM / 64, K_DIM / 64), 256, 0, stream>>>(prev, Pt);
    logic_gemm_kernel<<<dim3(N_DIM / BN, M_DIM / BM), 512, 0, stream>>>(Pa, Pb, Pt, C4, out);
}

// Round 7
// 144.997 us; speedup vs baseline: 1.1853x; 1.1853x over previous
//
#include <hip/hip_runtime.h>
#include <hip/hip_bf16.h>

#define M_DIM 2048   // size
#define K_DIM 2048   // prev_size
#define N_DIM 8192   // batch

#define BM 128
#define BN 256
#define BK 64
#define NT (K_DIM / BK)   // 32 K-tiles

typedef __attribute__((ext_vector_type(4))) float f32x4;
typedef __attribute__((ext_vector_type(8))) short s16x8;

static __device__ __forceinline__ ushort f2bf(float x) {
    __hip_bfloat16 h = __float2bfloat16(x);
    return *reinterpret_cast<ushort*>(&h);
}

// async global->LDS: each lane contributes 16B; LDS dest is wave-uniform base,
// hardware writes base + lane*16 (linear).
static __device__ __forceinline__ void stage1k(const ushort* g, ushort* l) {
    __builtin_amdgcn_global_load_lds(
        (const __attribute__((address_space(1))) void*)g,
        (__attribute__((address_space(3))) void*)l, 16, 0, 0);
}

// ---------------- softmax over rows of Wa/Wb -> bf16 probabilities ----------
__global__ __launch_bounds__(256) void softmax_rows_kernel(
    const float* __restrict__ Wa, const float* __restrict__ Wb,
    ushort* __restrict__ Pa, ushort* __restrict__ Pb)
{
    const float* W = blockIdx.y ? Wb : Wa;
    ushort* P = blockIdx.y ? Pb : Pa;
    const int row = blockIdx.x;
    const int t = threadIdx.x;
    const float* w = W + (size_t)row * K_DIM + t * 8;
    float4 v0 = *(const float4*)(w);
    float4 v1 = *(const float4*)(w + 4);
    float x[8] = {v0.x, v0.y, v0.z, v0.w, v1.x, v1.y, v1.z, v1.w};

    float m = x[0];
#pragma unroll
    for (int i = 1; i < 8; ++i) m = fmaxf(m, x[i]);
#pragma unroll
    for (int off = 32; off >= 1; off >>= 1) m = fmaxf(m, __shfl_xor(m, off));
    __shared__ float redm[4], reds[4];
    const int wid = t >> 6;
    if ((t & 63) == 0) redm[wid] = m;
    __syncthreads();
    m = fmaxf(fmaxf(redm[0], redm[1]), fmaxf(redm[2], redm[3]));

    float s = 0.f;
#pragma unroll
    for (int i = 0; i < 8; ++i) { x[i] = __expf(x[i] - m); s += x[i]; }
#pragma unroll
    for (int off = 32; off >= 1; off >>= 1) s += __shfl_xor(s, off);
    if ((t & 63) == 0) reds[wid] = s;
    __syncthreads();
    s = reds[0] + reds[1] + reds[2] + reds[3];
    const float inv = 1.0f / s;

    union { ushort u[8]; int4 v; } pk;
#pragma unroll
    for (int i = 0; i < 8; ++i) pk.u[i] = f2bf(x[i] * inv);
    *(int4*)(P + (size_t)row * K_DIM + t * 8) = pk.v;
}

// ---------- table softmax (over 16) contracted with gate coeffs -> c[4][M] --
__global__ __launch_bounds__(256) void table_c_kernel(
    const float* __restrict__ TW, float4* __restrict__ C4)
{
    const int s = blockIdx.x * 256 + threadIdx.x;
    if (s >= M_DIM) return;
    float x[16];
    float m = -1e30f;
#pragma unroll
    for (int t = 0; t < 16; ++t) { x[t] = TW[t * M_DIM + s]; m = fmaxf(m, x[t]); }
    float sum = 0.f;
#pragma unroll
    for (int t = 0; t < 16; ++t) { x[t] = __expf(x[t] - m); sum += x[t]; }
    const float inv = 1.0f / sum;

    const float c0a[16] = {0,0,0,0,0,0,0,0, 1,1,1,1,1,1,1,1};
    const float cAa[16] = {0,0,1,1,0,0,1,1, -1,-1,0,0,-1,-1,0,0};
    const float cBa[16] = {0,0,0,0,1,1,1,1, -1,-1,-1,-1,0,0,0,0};
    const float cXa[16] = {0,1,-1,0,-1,0,-2,-1, 1,2,0,1,0,1,-1,0};
    float c0 = 0.f, cA = 0.f, cB = 0.f, cX = 0.f;
#pragma unroll
    for (int t = 0; t < 16; ++t) {
        const float p = x[t] * inv;
        c0 += p * c0a[t]; cA += p * cAa[t]; cB += p * cBa[t]; cX += p * cXa[t];
    }
    C4[s] = make_float4(c0, cA, cB, cX);
}

// ---------- prev [K][N] f32 -> prevT [N][K] bf16 (transpose + convert) ------
__global__ __launch_bounds__(256) void transp_conv_kernel(
    const float* __restrict__ src, ushort* __restrict__ dst)
{
    __shared__ ushort tile[64][72];
    const int n0 = blockIdx.x * 64;
    const int k0 = blockIdx.y * 64;
    const int t = threadIdx.x;
#pragma unroll
    for (int it = 0; it < 4; ++it) {
        const int lin = it * 256 + t;      // 0..1023
        const int k = lin >> 4;            // 0..63
        const int n4 = (lin & 15) * 4;     // 0..60
        float4 v = *(const float4*)(src + (size_t)(k0 + k) * N_DIM + n0 + n4);
        tile[n4 + 0][k] = f2bf(v.x);
        tile[n4 + 1][k] = f2bf(v.y);
        tile[n4 + 2][k] = f2bf(v.z);
        tile[n4 + 3][k] = f2bf(v.w);
    }
    __syncthreads();
#pragma unroll
    for (int it = 0; it < 2; ++it) {
        const int lin = it * 256 + t;      // 0..511
        const int n = lin >> 3;            // 0..63
        const int k8 = (lin & 7) * 8;      // 0..56
        int4 v = *(const int4*)&tile[n][k8];
        *(int4*)(dst + (size_t)(n0 + n) * K_DIM + k0 + k8) = v;
    }
}

// ------------- dual GEMM, pipelined 4-phase schedule + gate epilogue --------
// Same barrier/vmcnt ledger as the verified R5 kernel (16x16x32, conflicts=0).
// Difference vs R5: NO manual lgkmcnt(0) fences / sched_barrier(0) pins.
// Fragment reads are plain loads feeding MFMAs (true data deps) -> compiler
// emits counted lgkmcnt and may slide reads/stages under MFMA clusters.
// Hazard audit (unchanged ledger): every LDS region's last read is consumed
// by an MFMA (lgkm-drained) >= 1 barrier before the stage that overwrites it
// issues; stage visibility is licensed by {per-wave vmcnt guard -> barrier}.
//
// Stage pairs (2 loads each) for tile T:
//   A(T)@ph2(T-2), B(T)@ph3(T-2), C(T)@ph4(T-2), D(T)@ph1(T-1)
// Guards: vmcnt(6) at ph1 (drains D(t)), vmcnt(6) at ph3 (drains A,B(t+1)).
// Tail (kt >= NT-2): vmcnt(0).

#define MFMA8(ACC, FA, FP, MI0)                                                \
    _Pragma("unroll") for (int mi = (MI0); mi < (MI0) + 2; ++mi)               \
    _Pragma("unroll") for (int ni = 0; ni < 4; ++ni)                           \
        ACC[mi][ni] = __builtin_amdgcn_mfma_f32_16x16x32_bf16(                 \
            FA[mi], FP[ni], ACC[mi][ni], 0, 0, 0);

#define STAGE_A(T) do { const int b_ = (T) & 1; const int o_ = (T) * BK;       \
    stage1k(gPa + o_,  &sPa[b_][0][wid * 16][0]);                              \
    stage1k(gPt0 + o_, &sPt[b_][0][wid * 16][0]); } while (0)
#define STAGE_B(T) do { const int b_ = (T) & 1; const int o_ = (T) * BK;       \
    stage1k(gPt1 + o_, &sPt[b_][0][128 + wid * 16][0]);                        \
    stage1k(gPb + o_,  &sPb[b_][0][wid * 16][0]); } while (0)
#define STAGE_C(T) do { const int b_ = (T) & 1; const int o_ = (T) * BK + 32;  \
    stage1k(gPa + o_,  &sPa[b_][1][wid * 16][0]);                              \
    stage1k(gPt0 + o_, &sPt[b_][1][wid * 16][0]); } while (0)
#define STAGE_D(T) do { const int b_ = (T) & 1; const int o_ = (T) * BK + 32;  \
    stage1k(gPt1 + o_, &sPt[b_][1][128 + wid * 16][0]);                        \
    stage1k(gPb + o_,  &sPb[b_][1][wid * 16][0]); } while (0)

__global__ __launch_bounds__(512, 2) void logic_gemm_kernel(
    const ushort* __restrict__ Pa,   // [M][K] bf16
    const ushort* __restrict__ Pb,   // [M][K] bf16
    const ushort* __restrict__ Pt,   // prevT [N][K] bf16
    const float4* __restrict__ C4,   // [M]
    float* __restrict__ out)         // [M][N]
{
    __shared__ ushort sPa[2][2][128][32];   // 32 KB
    __shared__ ushort sPb[2][2][128][32];   // 32 KB
    __shared__ ushort sPt[2][2][256][32];   // 64 KB

    const int m0 = blockIdx.y * BM;
    const int n0 = blockIdx.x * BN;
    const int t = threadIdx.x;
    const int wid = t >> 6, lane = t & 63;
    const int wr = wid >> 2, wc = wid & 3;   // 2M x 4N waves, 64x64 out each
    const int lq = lane >> 4, lr = lane & 15;

    // staging: lane -> region row (lane>>2), pre-swizzled source col
    const int srow = lane >> 2;                               // 0..15
    const int scol = (((lane & 3) ^ ((lane >> 3) & 3)) << 3); // {0,8,16,24}
    const ushort* gPa  = Pa + (size_t)(m0 + wid * 16 + srow) * K_DIM + scol;
    const ushort* gPb  = Pb + (size_t)(m0 + wid * 16 + srow) * K_DIM + scol;
    const ushort* gPt0 = Pt + (size_t)(n0 + wid * 16 + srow) * K_DIM + scol;
    const ushort* gPt1 = gPt0 + (size_t)128 * K_DIM;

    // ds_read byte offsets (swizzled): row*64 + 16*(lq ^ sigma(row)),
    // sigma(r) = (r>>1)&3 -> conflict-free (verified R4/R5: conflicts = 0)
    const int cswz = (lq ^ ((lr >> 1) & 3)) << 4;
    const int roA = (wr * 64 + lr) * 64 + cswz;   // within [128][32] region
    const int roP = (wc * 64 + lr) * 64 + cswz;   // within [256][32] region

    f32x4 accA[4][4] = {};
    f32x4 accB[4][4] = {};
    s16x8 fX0[4], fX1[4], fpA[4], fpB[4];

    // prologue: A,B,C,D(0), A,B,C(1) = 14 loads; drain first 4 (A,B(0));
    // barrier; pre-read tile-0 kh0 fragments.
    STAGE_A(0); STAGE_B(0); STAGE_C(0); STAGE_D(0);
    STAGE_A(1); STAGE_B(1); STAGE_C(1);
    asm volatile("s_waitcnt vmcnt(10)" ::: "memory");
    __builtin_amdgcn_s_barrier();
#pragma unroll
    for (int i = 0; i < 4; ++i)
        fX0[i] = *(const s16x8*)((const char*)&sPa[0][0][0][0] + roA + i * 1024);
#pragma unroll
    for (int i = 0; i < 4; ++i)
        fpA[i] = *(const s16x8*)((const char*)&sPt[0][0][0][0] + roP + i * 1024);

    for (int kt = 0; kt < NT; ++kt) {
        const int buf = kt & 1;
        const char* bA1 = (const char*)&sPa[buf][1][0][0];
        const char* bB0 = (const char*)&sPb[buf][0][0][0];
        const char* bB1 = (const char*)&sPb[buf][1][0][0];
        const char* bP1 = (const char*)&sPt[buf][1][0][0];
        const char* nA0 = (const char*)&sPa[buf ^ 1][0][0][0];
        const char* nP0 = (const char*)&sPt[buf ^ 1][0][0][0];

        // -------- phase 1: accA x kh0 (uses fX0, fpA) --------
        __builtin_amdgcn_s_setprio(1);
        MFMA8(accA, fX0, fpA, 0);
        __builtin_amdgcn_s_setprio(0);
        if (kt < NT - 2) asm volatile("s_waitcnt vmcnt(6)" ::: "memory");
        else             asm volatile("s_waitcnt vmcnt(0)" ::: "memory");
#pragma unroll
        for (int i = 0; i < 4; ++i) fX1[i] = *(const s16x8*)(bB0 + roA + i * 1024);
        if (kt + 1 < NT) STAGE_D(kt + 1);
        __builtin_amdgcn_s_setprio(1);
        MFMA8(accA, fX0, fpA, 2);
        __builtin_amdgcn_s_setprio(0);
        __builtin_amdgcn_s_barrier();

        // -------- phase 2: accB x kh0 (uses fX1, fpA) --------
        __builtin_amdgcn_s_setprio(1);
        MFMA8(accB, fX1, fpA, 0);
        __builtin_amdgcn_s_setprio(0);
#pragma unroll
        for (int i = 0; i < 4; ++i) fX0[i] = *(const s16x8*)(bA1 + roA + i * 1024);
#pragma unroll
        for (int i = 0; i < 4; ++i) fpB[i] = *(const s16x8*)(bP1 + roP + i * 1024);
        if (kt + 2 < NT) STAGE_A(kt + 2);
        __builtin_amdgcn_s_setprio(1);
        MFMA8(accB, fX1, fpA, 2);
        __builtin_amdgcn_s_setprio(0);
        __builtin_amdgcn_s_barrier();

        // -------- phase 3: accA x kh1 (uses fX0, fpB) --------
        __builtin_amdgcn_s_setprio(1);
        MFMA8(accA, fX0, fpB, 0);
        __builtin_amdgcn_s_setprio(0);
        if (kt < NT - 2) asm volatile("s_waitcnt vmcnt(6)" ::: "memory");
        else             asm volatile("s_waitcnt vmcnt(0)" ::: "memory");
#pragma unroll
        for (int i = 0; i < 4; ++i) fX1[i] = *(const s16x8*)(bB1 + roA + i * 1024);
        if (kt + 2 < NT) STAGE_B(kt + 2);
        __builtin_amdgcn_s_setprio(1);
        MFMA8(accA, fX0, fpB, 2);
        __builtin_amdgcn_s_setprio(0);
        __builtin_amdgcn_s_barrier();

        // -------- phase 4: accB x kh1 (uses fX1, fpB) --------
        __builtin_amdgcn_s_setprio(1);
        MFMA8(accB, fX1, fpB, 0);
        __builtin_amdgcn_s_setprio(0);
#pragma unroll
        for (int i = 0; i < 4; ++i) fX0[i] = *(const s16x8*)(nA0 + roA + i * 1024);
#pragma unroll
        for (int i = 0; i < 4; ++i) fpA[i] = *(const s16x8*)(nP0 + roP + i * 1024);
        if (kt + 2 < NT) STAGE_C(kt + 2);
        __builtin_amdgcn_s_setprio(1);
        MFMA8(accB, fX1, fpB, 2);
        __builtin_amdgcn_s_setprio(0);
        __builtin_amdgcn_s_barrier();
    }

    // epilogue: out = c0 + cA*A + cB*B + cAB*A*B
#pragma unroll
    for (int mi = 0; mi < 4; ++mi) {
#pragma unroll
        for (int i = 0; i < 4; ++i) {
            const int row = m0 + wr * 64 + mi * 16 + lq * 4 + i;
            const float4 c = C4[row];
#pragma unroll
            for (int ni = 0; ni < 4; ++ni) {
                const int col = n0 + wc * 64 + ni * 16 + lr;
                const float Av = accA[mi][ni][i];
                const float Bv = accB[mi][ni][i];
                out[(size_t)row * N_DIM + col] = c.x + c.y * Av + c.z * Bv + c.w * Av * Bv;
            }
        }
    }
}

extern "C" void kernel_launch(void* const* d_in, const int* in_sizes, int n_in,
                              void* d_out, int out_size, void* d_ws, size_t ws_size,
                              hipStream_t stream) {
    const float* prev = (const float*)d_in[0];   // [2048][8192]
    const float* Wa   = (const float*)d_in[1];   // [2048][2048]
    const float* Wb   = (const float*)d_in[2];   // [2048][2048]
    const float* TW   = (const float*)d_in[3];   // [16][2048]
    float* out = (float*)d_out;                  // [2048][8192]

    char* ws = (char*)d_ws;
    ushort* Pa = (ushort*)(ws);                          //  8 MiB
    ushort* Pb = (ushort*)(ws + (size_t)(8u << 20));     //  8 MiB
    ushort* Pt = (ushort*)(ws + (size_t)(16u << 20));    // 32 MiB
    float4* C4 = (float4*)(ws + (size_t)(48u << 20));    // 32 KiB

    softmax_rows_kernel<<<dim3(2048, 2), 256, 0, stream>>>(Wa, Wb, Pa, Pb);
    table_c_kernel<<<dim3(8), 256, 0, stream>>>(TW, C4);
    transp_conv_kernel<<<dim3(N_DIM / 64, K_DIM / 64), 256, 0, stream>>>(prev, Pt);
    logic_gemm_kernel<<<dim3(N_DIM / BN, M_DIM / BM), 512, 0, stream>>>(Pa, Pb, Pt, C4, out);
}